// Round 10
// baseline (494.208 us; speedup 1.0000x reference)
//
#include <hip/hip_runtime.h>
#include <math.h>

// GAT, N=4096, ~1% adjacency. R10: widened gathers — ushort4 (8B)/lane, two
// neighbors per wave (half = lane>>5, 32 lanes x 4 cols = 128-col tile), final
// shfl_xor(32) combine. Halves gather VALU-per-byte (R9 profile: gather3 was
// VALU-issue-bound at 53% VALUBusy, 4B loads). Rest identical to R9
// (fp16 end-to-end, single-pass MFMA GEMM, XCD-pinned column tiles).

#define N_NODES 4096
#define MAXNB 128
#define BM 128
#define BN 128
#define BK 32

typedef _Float16 f16x8 __attribute__((ext_vector_type(8)));
typedef float f32x4 __attribute__((ext_vector_type(4)));

#define GLL(gp, lp)                                                     \
  __builtin_amdgcn_global_load_lds(                                     \
      (const __attribute__((address_space(1))) void*)(gp),              \
      (__attribute__((address_space(3))) void*)(lp), 16, 0, 0)

// ---------------- fp16 helpers ----------------
union U16 {
  unsigned short u;
  _Float16 h;
};
__device__ __forceinline__ float h2f(unsigned short u) {
  U16 x;
  x.u = u;
  return (float)x.h;
}
__device__ __forceinline__ unsigned short f2h(float f) {
  U16 x;
  x.h = (_Float16)f;  // RNE
  return x.u;
}

// ---------------- reduction helpers (blockDim == 256) ----------------
__device__ __forceinline__ float wave_sum(float v) {
#pragma unroll
  for (int o = 32; o > 0; o >>= 1) v += __shfl_xor(v, o);
  return v;
}
__device__ __forceinline__ float wave_max(float v) {
#pragma unroll
  for (int o = 32; o > 0; o >>= 1) v = fmaxf(v, __shfl_xor(v, o));
  return v;
}
__device__ __forceinline__ float block_sum(float v, float* buf) {
  v = wave_sum(v);
  __syncthreads();
  if ((threadIdx.x & 63) == 0) buf[threadIdx.x >> 6] = v;
  __syncthreads();
  return buf[0] + buf[1] + buf[2] + buf[3];
}
__device__ __forceinline__ float block_max(float v, float* buf) {
  v = wave_max(v);
  __syncthreads();
  if ((threadIdx.x & 63) == 0) buf[threadIdx.x >> 6] = v;
  __syncthreads();
  return fmaxf(fmaxf(buf[0], buf[1]), fmaxf(buf[2], buf[3]));
}

// ---------------- zero f-buffers ----------------
__global__ __launch_bounds__(256) void zero_f(float* __restrict__ p, int n) {
  int i = blockIdx.x * 256 + threadIdx.x;
  if (i < n) p[i] = 0.f;
}

// ---------------- CSR build ----------------
__global__ __launch_bounds__(256) void build_csr(const float* __restrict__ adj,
                                                 int* __restrict__ cnt,
                                                 int* __restrict__ idx) {
  __shared__ int c;
  if (threadIdx.x == 0) c = 0;
  __syncthreads();
  const int row = blockIdx.x;
  const float* arow = adj + (size_t)row * N_NODES;
  for (int b = 0; b < N_NODES; b += 256) {
    float v = arow[b + threadIdx.x];
    if (v > 0.f) {
      int p = atomicAdd(&c, 1);
      if (p < MAXNB) idx[row * MAXNB + p] = b + threadIdx.x;
    }
  }
  __syncthreads();
  if (threadIdx.x == 0) cnt[row] = c < MAXNB ? c : MAXNB;
}

// ---------------- elementwise fp32 -> fp16 ----------------
__global__ __launch_bounds__(256) void convert_h(const float* __restrict__ in,
                                                 unsigned short* __restrict__ oh,
                                                 int n4) {
  int i = blockIdx.x * 256 + threadIdx.x;
  if (i >= n4) return;
  float4 v = ((const float4*)in)[i];
  ushort4 h;
  h.x = f2h(v.x);
  h.y = f2h(v.y);
  h.z = f2h(v.z);
  h.w = f2h(v.w);
  ((ushort4*)oh)[i] = h;
}

// ---------------- W [H][K][D] fp32 -> Bt [H*D][K] fp16 ----------------
__global__ __launch_bounds__(256) void convert_w(const float* __restrict__ W,
                                                 unsigned short* __restrict__ th,
                                                 int K, int D) {
  __shared__ float t[32][33];
  const int h = blockIdx.z;
  const int k0 = blockIdx.x * 32, d0 = blockIdx.y * 32;
  const int tx = threadIdx.x & 31, ty = threadIdx.x >> 5;
  const float* Wp = W + (size_t)h * K * D;
#pragma unroll
  for (int r = 0; r < 4; r++)
    t[ty + r * 8][tx] = Wp[(size_t)(k0 + ty + r * 8) * D + d0 + tx];
  __syncthreads();
#pragma unroll
  for (int r = 0; r < 4; r++) {
    int d = ty + r * 8;
    th[(size_t)(h * D + d0 + d) * K + k0 + tx] = f2h(t[tx][d]);
  }
}

// ---------------- fp16 MFMA GEMM: 128x128 tile, dbuf, conflict-free swizzle ----------------
__global__ __launch_bounds__(256) void gemm_mfma(
    const unsigned short* __restrict__ A, const unsigned short* __restrict__ B,
    unsigned short* __restrict__ Cb, float* __restrict__ f1,
    float* __restrict__ f2, const float* __restrict__ af, int K, int Ntot, int D) {
  __shared__ unsigned short lds[2][2][BM * BK];  // 32 KB: [buf][A,B]

  const int tid = threadIdx.x;
  const int w = tid >> 6, lane = tid & 63;
  const int wm = w >> 1, wn = w & 1;
  const int quad = lane >> 4, l16 = lane & 15;
  const int m0 = blockIdx.x * BM, n0 = blockIdx.y * BN;

  const int s0 = w * 128 + lane, s1 = s0 + 64;
  const int r0 = s0 >> 2, q0 = (s0 & 3) ^ ((r0 >> 1) & 3);
  const int r1 = s1 >> 2, q1 = (s1 & 3) ^ ((r1 >> 1) & 3);
  const size_t offA0 = (size_t)(m0 + r0) * K + q0 * 8;
  const size_t offA1 = (size_t)(m0 + r1) * K + q1 * 8;
  const size_t offB0 = (size_t)(n0 + r0) * K + q0 * 8;
  const size_t offB1 = (size_t)(n0 + r1) * K + q1 * 8;

#define STAGE(b, k0)                                \
  do {                                              \
    GLL(A + offA0 + (k0), &lds[b][0][s0 * 8]);      \
    GLL(A + offA1 + (k0), &lds[b][0][s1 * 8]);      \
    GLL(B + offB0 + (k0), &lds[b][1][s0 * 8]);      \
    GLL(B + offB1 + (k0), &lds[b][1][s1 * 8]);      \
  } while (0)

  f32x4 acc[4][4];
#pragma unroll
  for (int i = 0; i < 4; i++)
#pragma unroll
    for (int j = 0; j < 4; j++) acc[i][j] = (f32x4){0.f, 0.f, 0.f, 0.f};

  int posA[4], posB[4];
#pragma unroll
  for (int i = 0; i < 4; i++) {
    int ra = wm * 64 + i * 16 + l16;
    posA[i] = (ra * 4 + (quad ^ ((ra >> 1) & 3))) * 8;
    int rb = wn * 64 + i * 16 + l16;
    posB[i] = (rb * 4 + (quad ^ ((rb >> 1) & 3))) * 8;
  }

  const int KT = K / BK;
  STAGE(0, 0);
  for (int kt = 0; kt < KT; kt++) {
    const int cur = kt & 1;
    __syncthreads();
    if (kt + 1 < KT) STAGE(cur ^ 1, (kt + 1) * BK);

    f16x8 fa[4], fb[4];
#pragma unroll
    for (int i = 0; i < 4; i++) {
      fa[i] = *(const f16x8*)&lds[cur][0][posA[i]];
      fb[i] = *(const f16x8*)&lds[cur][1][posB[i]];
    }
#pragma unroll
    for (int i = 0; i < 4; i++)
#pragma unroll
      for (int j = 0; j < 4; j++)
        acc[i][j] = __builtin_amdgcn_mfma_f32_16x16x32_f16(fa[i], fb[j],
                                                           acc[i][j], 0, 0, 0);
  }
#undef STAGE

  // epilogue 1: fp16 C write (C/D layout: col=l16, row=quad*4+r)
  const int gm = m0 + wm * 64 + quad * 4;
  const int gn = n0 + wn * 64 + l16;
#pragma unroll
  for (int i = 0; i < 4; i++)
#pragma unroll
    for (int j = 0; j < 4; j++) {
      unsigned short* p = Cb + (size_t)(gm + i * 16) * Ntot + gn + j * 16;
#pragma unroll
      for (int r = 0; r < 4; r++) p[(size_t)r * Ntot] = f2h(acc[i][j][r]);
    }

  // epilogue 2: exact f1/f2 from fp32 acc
  const int h = n0 / D;
  const int d0 = (n0 % D) + wn * 64 + l16;
  float a1v[4], a2v[4];
#pragma unroll
  for (int j = 0; j < 4; j++) {
    a1v[j] = af[h * 2 * D + d0 + j * 16];
    a2v[j] = af[h * 2 * D + D + d0 + j * 16];
  }
#pragma unroll
  for (int i = 0; i < 4; i++)
#pragma unroll
    for (int r = 0; r < 4; r++) {
      float s1 = 0.f, s2 = 0.f;
#pragma unroll
      for (int j = 0; j < 4; j++) {
        s1 += acc[i][j][r] * a1v[j];
        s2 += acc[i][j][r] * a2v[j];
      }
#pragma unroll
      for (int m = 1; m < 16; m <<= 1) {
        s1 += __shfl_xor(s1, m);
        s2 += __shfl_xor(s2, m);
      }
      if (l16 == 0) {
        int row = gm + i * 16 + r;
        atomicAdd(&f1[h * N_NODES + row], s1);
        atomicAdd(&f2[h * N_NODES + row], s2);
      }
    }
}

// ---------------- attention weights: softmax over neighbors, per head ----------------
__global__ __launch_bounds__(256) void attw(const float* __restrict__ f1,
                                            const float* __restrict__ f2,
                                            const int* __restrict__ cnt,
                                            const int* __restrict__ idxs,
                                            float* __restrict__ wgt, int H,
                                            float scale) {
  __shared__ int nbs[MAXNB];
  __shared__ float buf[4];
  const int n = blockIdx.x, tid = threadIdx.x;
  const int c = cnt[n];
  if (tid < c) nbs[tid] = idxs[n * MAXNB + tid];
  __syncthreads();
  for (int h = 0; h < H; h++) {
    float e = -3.0e38f;
    if (tid < c) {
      float s = f1[h * N_NODES + n] + f2[h * N_NODES + nbs[tid]];
      e = s >= 0.f ? s : 0.2f * s;  // leaky_relu
    }
    float m = block_max(e, buf);
    float wj = (tid < c) ? __expf(e - m) : 0.f;
    float tot = block_sum(wj, buf);
    if (tid < c) wgt[((size_t)h * N_NODES + n) * MAXNB + tid] = wj / tot * scale;
  }
}

// ---------------- layers 1&2 gather: 8 XCD-pinned 128-col tiles ----------------
// One wave per node; half = lane>>5 processes neighbor jj = j + half;
// 32 lanes x ushort4 = 128 cols. Final shfl_xor(32) combine; lanes<32 write.
__global__ __launch_bounds__(256) void gather12(
    const unsigned short* __restrict__ Whb, const float* __restrict__ wgt,
    const int* __restrict__ cnt, const int* __restrict__ idxs,
    unsigned short* __restrict__ hh) {
  __shared__ int snb[4][MAXNB];
  __shared__ float swt[4][MAXNB];
  const int t = blockIdx.x & 7;
  const int g = blockIdx.x >> 3;
  const int tid = threadIdx.x;
  const int h = t >> 1;  // 2 tiles per head (D=256)
  for (int i = tid; i < 4 * MAXNB; i += 256) {
    int ni = i >> 7, j = i & (MAXNB - 1);
    snb[ni][j] = idxs[(g * 4 + ni) * MAXNB + j];
    swt[ni][j] = wgt[((size_t)h * N_NODES + g * 4 + ni) * MAXNB + j];
  }
  __syncthreads();
  const int w = tid >> 6, lane = tid & 63;
  const int half = lane >> 5, c32 = lane & 31;
  const int n = g * 4 + w;
  const int c = cnt[n];
  const int col = t * 128 + c32 * 4;
  float a0 = 0.f, a1 = 0.f, a2 = 0.f, a3 = 0.f;
  for (int j = half; j < c; j += 2) {
    const int nb = snb[w][j];
    const float wv = swt[w][j];
    ushort4 v = *(const ushort4*)(Whb + (size_t)nb * 1024 + col);
    a0 += wv * h2f(v.x);
    a1 += wv * h2f(v.y);
    a2 += wv * h2f(v.z);
    a3 += wv * h2f(v.w);
  }
  a0 += __shfl_xor(a0, 32);
  a1 += __shfl_xor(a1, 32);
  a2 += __shfl_xor(a2, 32);
  a3 += __shfl_xor(a3, 32);
  if (half == 0) {
    float o[4] = {a0, a1, a2, a3};
    ushort4 oh;
#pragma unroll
    for (int s = 0; s < 4; s++) {
      float v = o[s];
      v = v > 0.f ? v : __expf(v) - 1.f;  // elu (per-head)
      v = v > 0.f ? v : __expf(v) - 1.f;  // elu (post-concat)
      ((unsigned short*)&oh)[s] = f2h(v);
    }
    *(ushort4*)(hh + (size_t)n * 1024 + col) = oh;
  }
}

// ---------------- layer 3 gather: 24 XCD-pinned 128-col tiles ----------------
__global__ __launch_bounds__(256) void gather3(
    const unsigned short* __restrict__ Whb, const float* __restrict__ wgt,
    const int* __restrict__ cnt, const int* __restrict__ idxs,
    unsigned short* __restrict__ aggb) {
  __shared__ int snb[4][MAXNB];
  __shared__ float swt[4][MAXNB];
  const int t = blockIdx.x % 24;
  const int g = blockIdx.x / 24;
  const int tid = threadIdx.x;
  const int h = t >> 2;  // 4 tiles per head (D=512)
  for (int i = tid; i < 4 * MAXNB; i += 256) {
    int ni = i >> 7, j = i & (MAXNB - 1);
    snb[ni][j] = idxs[(g * 4 + ni) * MAXNB + j];
    swt[ni][j] = wgt[((size_t)h * N_NODES + g * 4 + ni) * MAXNB + j];
  }
  __syncthreads();
  const int w = tid >> 6, lane = tid & 63;
  const int half = lane >> 5, c32 = lane & 31;
  const int n = g * 4 + w;
  const int c = cnt[n];
  const int col = t * 128 + c32 * 4;    // global col in 3072
  const int cc = col - h * 512;         // col within head
  float a0 = 0.f, a1 = 0.f, a2 = 0.f, a3 = 0.f;
  for (int j = half; j < c; j += 2) {
    const int nb = snb[w][j];
    const float wv = swt[w][j];
    ushort4 v = *(const ushort4*)(Whb + (size_t)nb * 3072 + col);
    a0 += wv * h2f(v.x);
    a1 += wv * h2f(v.y);
    a2 += wv * h2f(v.z);
    a3 += wv * h2f(v.w);
  }
  a0 += __shfl_xor(a0, 32);
  a1 += __shfl_xor(a1, 32);
  a2 += __shfl_xor(a2, 32);
  a3 += __shfl_xor(a3, 32);
  if (half == 0) {
    ushort4 o;
    o.x = f2h(a0);
    o.y = f2h(a1);
    o.z = f2h(a2);
    o.w = f2h(a3);
    *(ushort4*)(aggb + ((size_t)h * N_NODES + n) * 512 + cc) = o;
  }
}

// ---------------- layer 3 reduce: head-sum + elu + L2-normalize ----------------
__global__ __launch_bounds__(256) void reduce3(const unsigned short* __restrict__ aggb,
                                               float* __restrict__ out) {
  __shared__ float buf[4];
  const int n = blockIdx.x, tid = threadIdx.x;
  float v0 = 0.f, v1 = 0.f;
#pragma unroll
  for (int h = 0; h < 6; h++) {
    ushort2 u = *(const ushort2*)(aggb + ((size_t)h * N_NODES + n) * 512 + tid * 2);
    v0 += h2f(u.x);
    v1 += h2f(u.y);
  }
  v0 = v0 > 0.f ? v0 : __expf(v0) - 1.f;
  v1 = v1 > 0.f ? v1 : __expf(v1) - 1.f;
  float ss = block_sum(v0 * v0 + v1 * v1, buf);
  float inv = 1.f / fmaxf(sqrtf(ss), 1e-12f);
  out[(size_t)n * 512 + tid * 2] = v0 * inv;
  out[(size_t)n * 512 + tid * 2 + 1] = v1 * inv;
}

extern "C" void kernel_launch(void* const* d_in, const int* in_sizes, int n_in,
                              void* d_out, int out_size, void* d_ws, size_t ws_size,
                              hipStream_t stream) {
  (void)in_sizes; (void)n_in; (void)out_size; (void)ws_size;
  const float* x   = (const float*)d_in[0];  // [4096, 2048]
  const float* adj = (const float*)d_in[1];  // [4096, 4096]
  const float* W1  = (const float*)d_in[2];  // [4, 2048, 256]
  const float* a1  = (const float*)d_in[3];  // [4, 512]
  const float* W2  = (const float*)d_in[4];  // [4, 1024, 256]
  const float* a2  = (const float*)d_in[5];  // [4, 512]
  const float* W3  = (const float*)d_in[6];  // [6, 1024, 512]
  const float* a3  = (const float*)d_in[7];  // [6, 1024]
  float* out = (float*)d_out;                // [4096, 512]

  // workspace layout (~76 MB peak)
  char* ws = (char*)d_ws;
  size_t off = 0;
  auto alloc = [&](size_t bytes) {
    void* p = ws + off;
    off += (bytes + 255) & ~(size_t)255;
    return p;
  };
  int* nbr_cnt = (int*)alloc((size_t)N_NODES * 4);
  int* nbr_idx = (int*)alloc((size_t)N_NODES * MAXNB * 4);
  float* fbuf = (float*)alloc((size_t)28 * N_NODES * 4);
  unsigned short* Wt = (unsigned short*)alloc((size_t)6 * 1024 * 512 * 2);  // 6.3 MB
  unsigned short* Areg = (unsigned short*)alloc((size_t)N_NODES * 2048 * 2);  // 16.8 MB
  unsigned short* Whb = (unsigned short*)alloc((size_t)N_NODES * 3072 * 2);   // 25.2 MB
  unsigned short* aggb = (unsigned short*)alloc((size_t)6 * N_NODES * 512 * 2);  // 25.2 MB

  // Areg timeline: xh (dead after gemm1) -> [wgt12 8.4 MB | hh 8.4 MB] ->
  // after gemm3: wgt3 (12.6 MB, overlaps dead hh region start)
  unsigned short* xh = Areg;
  float* wgt12 = (float*)Areg;
  unsigned short* hh = Areg + (size_t)N_NODES * 1024;
  float* wgt3 = (float*)Areg;

  float* f1_1 = fbuf;
  float* f2_1 = fbuf + 4 * N_NODES;
  float* f1_2 = fbuf + 8 * N_NODES;
  float* f2_2 = fbuf + 12 * N_NODES;
  float* f1_3 = fbuf + 16 * N_NODES;
  float* f2_3 = fbuf + 22 * N_NODES;

  zero_f<<<(28 * N_NODES + 255) / 256, 256, 0, stream>>>(fbuf, 28 * N_NODES);
  build_csr<<<N_NODES, 256, 0, stream>>>(adj, nbr_cnt, nbr_idx);

  // ---- layer 1: A = x (K=2048), Ntot = 1024, D = 256 ----
  convert_h<<<(N_NODES * 2048 / 4 + 255) / 256, 256, 0, stream>>>(
      x, xh, N_NODES * 2048 / 4);
  convert_w<<<dim3(2048 / 32, 256 / 32, 4), 256, 0, stream>>>(W1, Wt, 2048, 256);
  gemm_mfma<<<dim3(N_NODES / BM, 1024 / BN), 256, 0, stream>>>(
      xh, Wt, Whb, f1_1, f2_1, a1, 2048, 1024, 256);
  attw<<<N_NODES, 256, 0, stream>>>(f1_1, f2_1, nbr_cnt, nbr_idx, wgt12, 4, 1.f);
  gather12<<<8 * (N_NODES / 4), 256, 0, stream>>>(Whb, wgt12, nbr_cnt, nbr_idx, hh);

  // ---- layer 2: A = h (K=1024), Ntot = 1024, D = 256 ----
  convert_w<<<dim3(1024 / 32, 256 / 32, 4), 256, 0, stream>>>(W2, Wt, 1024, 256);
  gemm_mfma<<<dim3(N_NODES / BM, 1024 / BN), 256, 0, stream>>>(
      hh, Wt, Whb, f1_2, f2_2, a2, 1024, 1024, 256);
  attw<<<N_NODES, 256, 0, stream>>>(f1_2, f2_2, nbr_cnt, nbr_idx, wgt12, 4, 1.f);
  gather12<<<8 * (N_NODES / 4), 256, 0, stream>>>(Whb, wgt12, nbr_cnt, nbr_idx, hh);

  // ---- layer 3: A = h (K=1024), Ntot = 3072, D = 512 ----
  convert_w<<<dim3(1024 / 32, 512 / 32, 6), 256, 0, stream>>>(W3, Wt, 1024, 512);
  gemm_mfma<<<dim3(N_NODES / BM, 3072 / BN), 256, 0, stream>>>(
      hh, Wt, Whb, f1_3, f2_3, a3, 1024, 3072, 512);
  attw<<<N_NODES, 256, 0, stream>>>(f1_3, f2_3, nbr_cnt, nbr_idx, wgt3, 6, 1.f / 6.f);
  gather3<<<24 * (N_NODES / 4), 256, 0, stream>>>(Whb, wgt3, nbr_cnt, nbr_idx, aggb);
  reduce3<<<N_NODES, 256, 0, stream>>>(aggb, out);
}

// Round 11
// 445.795 us; speedup vs baseline: 1.1086x; 1.1086x over previous
//
#include <hip/hip_runtime.h>
#include <math.h>

// GAT, N=4096, ~1% adjacency. R11: revert gathers to R9 one-neighbor-per-wave
// (R10's two-neighbor split broke coalescing + MLP: 78->110us). New: LDS stages
// packed int2 {row byte-offset, weight bits} -> one ds_read_b64/iter, no per-iter
// shift; char* base addressing; unroll 4. Rest = R9 (fp16 end-to-end, single-pass
// MFMA GEMM w/ exact f1/f2 epilogue, XCD-pinned 128-col gather tiles).

#define N_NODES 4096
#define MAXNB 128
#define BM 128
#define BN 128
#define BK 32

typedef _Float16 f16x8 __attribute__((ext_vector_type(8)));
typedef float f32x4 __attribute__((ext_vector_type(4)));

#define GLL(gp, lp)                                                     \
  __builtin_amdgcn_global_load_lds(                                     \
      (const __attribute__((address_space(1))) void*)(gp),              \
      (__attribute__((address_space(3))) void*)(lp), 16, 0, 0)

// ---------------- fp16 helpers ----------------
union U16 {
  unsigned short u;
  _Float16 h;
};
__device__ __forceinline__ float h2f(unsigned short u) {
  U16 x;
  x.u = u;
  return (float)x.h;
}
__device__ __forceinline__ unsigned short f2h(float f) {
  U16 x;
  x.h = (_Float16)f;  // RNE
  return x.u;
}

// ---------------- reduction helpers (blockDim == 256) ----------------
__device__ __forceinline__ float wave_sum(float v) {
#pragma unroll
  for (int o = 32; o > 0; o >>= 1) v += __shfl_xor(v, o);
  return v;
}
__device__ __forceinline__ float wave_max(float v) {
#pragma unroll
  for (int o = 32; o > 0; o >>= 1) v = fmaxf(v, __shfl_xor(v, o));
  return v;
}
__device__ __forceinline__ float block_sum(float v, float* buf) {
  v = wave_sum(v);
  __syncthreads();
  if ((threadIdx.x & 63) == 0) buf[threadIdx.x >> 6] = v;
  __syncthreads();
  return buf[0] + buf[1] + buf[2] + buf[3];
}
__device__ __forceinline__ float block_max(float v, float* buf) {
  v = wave_max(v);
  __syncthreads();
  if ((threadIdx.x & 63) == 0) buf[threadIdx.x >> 6] = v;
  __syncthreads();
  return fmaxf(fmaxf(buf[0], buf[1]), fmaxf(buf[2], buf[3]));
}

// ---------------- zero f-buffers ----------------
__global__ __launch_bounds__(256) void zero_f(float* __restrict__ p, int n) {
  int i = blockIdx.x * 256 + threadIdx.x;
  if (i < n) p[i] = 0.f;
}

// ---------------- CSR build ----------------
__global__ __launch_bounds__(256) void build_csr(const float* __restrict__ adj,
                                                 int* __restrict__ cnt,
                                                 int* __restrict__ idx) {
  __shared__ int c;
  if (threadIdx.x == 0) c = 0;
  __syncthreads();
  const int row = blockIdx.x;
  const float* arow = adj + (size_t)row * N_NODES;
  for (int b = 0; b < N_NODES; b += 256) {
    float v = arow[b + threadIdx.x];
    if (v > 0.f) {
      int p = atomicAdd(&c, 1);
      if (p < MAXNB) idx[row * MAXNB + p] = b + threadIdx.x;
    }
  }
  __syncthreads();
  if (threadIdx.x == 0) cnt[row] = c < MAXNB ? c : MAXNB;
}

// ---------------- elementwise fp32 -> fp16 ----------------
__global__ __launch_bounds__(256) void convert_h(const float* __restrict__ in,
                                                 unsigned short* __restrict__ oh,
                                                 int n4) {
  int i = blockIdx.x * 256 + threadIdx.x;
  if (i >= n4) return;
  float4 v = ((const float4*)in)[i];
  ushort4 h;
  h.x = f2h(v.x);
  h.y = f2h(v.y);
  h.z = f2h(v.z);
  h.w = f2h(v.w);
  ((ushort4*)oh)[i] = h;
}

// ---------------- W [H][K][D] fp32 -> Bt [H*D][K] fp16 ----------------
__global__ __launch_bounds__(256) void convert_w(const float* __restrict__ W,
                                                 unsigned short* __restrict__ th,
                                                 int K, int D) {
  __shared__ float t[32][33];
  const int h = blockIdx.z;
  const int k0 = blockIdx.x * 32, d0 = blockIdx.y * 32;
  const int tx = threadIdx.x & 31, ty = threadIdx.x >> 5;
  const float* Wp = W + (size_t)h * K * D;
#pragma unroll
  for (int r = 0; r < 4; r++)
    t[ty + r * 8][tx] = Wp[(size_t)(k0 + ty + r * 8) * D + d0 + tx];
  __syncthreads();
#pragma unroll
  for (int r = 0; r < 4; r++) {
    int d = ty + r * 8;
    th[(size_t)(h * D + d0 + d) * K + k0 + tx] = f2h(t[tx][d]);
  }
}

// ---------------- fp16 MFMA GEMM: 128x128 tile, dbuf, conflict-free swizzle ----------------
__global__ __launch_bounds__(256) void gemm_mfma(
    const unsigned short* __restrict__ A, const unsigned short* __restrict__ B,
    unsigned short* __restrict__ Cb, float* __restrict__ f1,
    float* __restrict__ f2, const float* __restrict__ af, int K, int Ntot, int D) {
  __shared__ unsigned short lds[2][2][BM * BK];  // 32 KB: [buf][A,B]

  const int tid = threadIdx.x;
  const int w = tid >> 6, lane = tid & 63;
  const int wm = w >> 1, wn = w & 1;
  const int quad = lane >> 4, l16 = lane & 15;
  const int m0 = blockIdx.x * BM, n0 = blockIdx.y * BN;

  const int s0 = w * 128 + lane, s1 = s0 + 64;
  const int r0 = s0 >> 2, q0 = (s0 & 3) ^ ((r0 >> 1) & 3);
  const int r1 = s1 >> 2, q1 = (s1 & 3) ^ ((r1 >> 1) & 3);
  const size_t offA0 = (size_t)(m0 + r0) * K + q0 * 8;
  const size_t offA1 = (size_t)(m0 + r1) * K + q1 * 8;
  const size_t offB0 = (size_t)(n0 + r0) * K + q0 * 8;
  const size_t offB1 = (size_t)(n0 + r1) * K + q1 * 8;

#define STAGE(b, k0)                                \
  do {                                              \
    GLL(A + offA0 + (k0), &lds[b][0][s0 * 8]);      \
    GLL(A + offA1 + (k0), &lds[b][0][s1 * 8]);      \
    GLL(B + offB0 + (k0), &lds[b][1][s0 * 8]);      \
    GLL(B + offB1 + (k0), &lds[b][1][s1 * 8]);      \
  } while (0)

  f32x4 acc[4][4];
#pragma unroll
  for (int i = 0; i < 4; i++)
#pragma unroll
    for (int j = 0; j < 4; j++) acc[i][j] = (f32x4){0.f, 0.f, 0.f, 0.f};

  int posA[4], posB[4];
#pragma unroll
  for (int i = 0; i < 4; i++) {
    int ra = wm * 64 + i * 16 + l16;
    posA[i] = (ra * 4 + (quad ^ ((ra >> 1) & 3))) * 8;
    int rb = wn * 64 + i * 16 + l16;
    posB[i] = (rb * 4 + (quad ^ ((rb >> 1) & 3))) * 8;
  }

  const int KT = K / BK;
  STAGE(0, 0);
  for (int kt = 0; kt < KT; kt++) {
    const int cur = kt & 1;
    __syncthreads();
    if (kt + 1 < KT) STAGE(cur ^ 1, (kt + 1) * BK);

    f16x8 fa[4], fb[4];
#pragma unroll
    for (int i = 0; i < 4; i++) {
      fa[i] = *(const f16x8*)&lds[cur][0][posA[i]];
      fb[i] = *(const f16x8*)&lds[cur][1][posB[i]];
    }
#pragma unroll
    for (int i = 0; i < 4; i++)
#pragma unroll
      for (int j = 0; j < 4; j++)
        acc[i][j] = __builtin_amdgcn_mfma_f32_16x16x32_f16(fa[i], fb[j],
                                                           acc[i][j], 0, 0, 0);
  }
#undef STAGE

  // epilogue 1: fp16 C write (C/D layout: col=l16, row=quad*4+r)
  const int gm = m0 + wm * 64 + quad * 4;
  const int gn = n0 + wn * 64 + l16;
#pragma unroll
  for (int i = 0; i < 4; i++)
#pragma unroll
    for (int j = 0; j < 4; j++) {
      unsigned short* p = Cb + (size_t)(gm + i * 16) * Ntot + gn + j * 16;
#pragma unroll
      for (int r = 0; r < 4; r++) p[(size_t)r * Ntot] = f2h(acc[i][j][r]);
    }

  // epilogue 2: exact f1/f2 from fp32 acc
  const int h = n0 / D;
  const int d0 = (n0 % D) + wn * 64 + l16;
  float a1v[4], a2v[4];
#pragma unroll
  for (int j = 0; j < 4; j++) {
    a1v[j] = af[h * 2 * D + d0 + j * 16];
    a2v[j] = af[h * 2 * D + D + d0 + j * 16];
  }
#pragma unroll
  for (int i = 0; i < 4; i++)
#pragma unroll
    for (int r = 0; r < 4; r++) {
      float s1 = 0.f, s2 = 0.f;
#pragma unroll
      for (int j = 0; j < 4; j++) {
        s1 += acc[i][j][r] * a1v[j];
        s2 += acc[i][j][r] * a2v[j];
      }
#pragma unroll
      for (int m = 1; m < 16; m <<= 1) {
        s1 += __shfl_xor(s1, m);
        s2 += __shfl_xor(s2, m);
      }
      if (l16 == 0) {
        int row = gm + i * 16 + r;
        atomicAdd(&f1[h * N_NODES + row], s1);
        atomicAdd(&f2[h * N_NODES + row], s2);
      }
    }
}

// ---------------- attention weights: softmax over neighbors, per head ----------------
__global__ __launch_bounds__(256) void attw(const float* __restrict__ f1,
                                            const float* __restrict__ f2,
                                            const int* __restrict__ cnt,
                                            const int* __restrict__ idxs,
                                            float* __restrict__ wgt, int H,
                                            float scale) {
  __shared__ int nbs[MAXNB];
  __shared__ float buf[4];
  const int n = blockIdx.x, tid = threadIdx.x;
  const int c = cnt[n];
  if (tid < c) nbs[tid] = idxs[n * MAXNB + tid];
  __syncthreads();
  for (int h = 0; h < H; h++) {
    float e = -3.0e38f;
    if (tid < c) {
      float s = f1[h * N_NODES + n] + f2[h * N_NODES + nbs[tid]];
      e = s >= 0.f ? s : 0.2f * s;  // leaky_relu
    }
    float m = block_max(e, buf);
    float wj = (tid < c) ? __expf(e - m) : 0.f;
    float tot = block_sum(wj, buf);
    if (tid < c) wgt[((size_t)h * N_NODES + n) * MAXNB + tid] = wj / tot * scale;
  }
}

// ---------------- layers 1&2 gather: 8 XCD-pinned 128-col tiles ----------------
// One wave per node, one neighbor per iteration (64 lanes x ushort2 = 256 B).
// LDS holds packed {row byte-offset, weight bits} -> one ds_read_b64/iter.
__global__ __launch_bounds__(256) void gather12(
    const unsigned short* __restrict__ Whb, const float* __restrict__ wgt,
    const int* __restrict__ cnt, const int* __restrict__ idxs,
    unsigned short* __restrict__ hh) {
  __shared__ int2 se[4][MAXNB];
  const int t = blockIdx.x & 7;
  const int g = blockIdx.x >> 3;
  const int tid = threadIdx.x;
  const int h = t >> 1;  // 2 tiles per head (D=256)
  for (int i = tid; i < 4 * MAXNB; i += 256) {
    int ni = i >> 7, j = i & (MAXNB - 1);
    int2 e;
    e.x = idxs[(g * 4 + ni) * MAXNB + j] * 2048;  // row bytes (1024 cols fp16)
    e.y = __float_as_int(wgt[((size_t)h * N_NODES + g * 4 + ni) * MAXNB + j]);
    se[ni][j] = e;
  }
  __syncthreads();
  const int w = tid >> 6, lane = tid & 63;
  const int n = g * 4 + w;
  const int c = cnt[n];
  const int col = t * 128 + lane * 2;
  const char* base = (const char*)Whb + (size_t)col * 2;
  float a0 = 0.f, a1 = 0.f;
#pragma unroll 4
  for (int j = 0; j < c; j++) {
    int2 e = se[w][j];
    ushort2 v = *(const ushort2*)(base + e.x);
    float wv = __int_as_float(e.y);
    a0 += wv * h2f(v.x);
    a1 += wv * h2f(v.y);
  }
  float o[2] = {a0, a1};
  ushort2 oh;
#pragma unroll
  for (int s = 0; s < 2; s++) {
    float v = o[s];
    v = v > 0.f ? v : __expf(v) - 1.f;  // elu (per-head)
    v = v > 0.f ? v : __expf(v) - 1.f;  // elu (post-concat)
    ((unsigned short*)&oh)[s] = f2h(v);
  }
  *(ushort2*)(hh + (size_t)n * 1024 + col) = oh;
}

// ---------------- layer 3 gather: 24 XCD-pinned 128-col tiles ----------------
__global__ __launch_bounds__(256) void gather3(
    const unsigned short* __restrict__ Whb, const float* __restrict__ wgt,
    const int* __restrict__ cnt, const int* __restrict__ idxs,
    unsigned short* __restrict__ aggb) {
  __shared__ int2 se[4][MAXNB];
  const int t = blockIdx.x % 24;
  const int g = blockIdx.x / 24;
  const int tid = threadIdx.x;
  const int h = t >> 2;  // 4 tiles per head (D=512)
  for (int i = tid; i < 4 * MAXNB; i += 256) {
    int ni = i >> 7, j = i & (MAXNB - 1);
    int2 e;
    e.x = idxs[(g * 4 + ni) * MAXNB + j] * 6144;  // row bytes (3072 cols fp16)
    e.y = __float_as_int(wgt[((size_t)h * N_NODES + g * 4 + ni) * MAXNB + j]);
    se[ni][j] = e;
  }
  __syncthreads();
  const int w = tid >> 6, lane = tid & 63;
  const int n = g * 4 + w;
  const int c = cnt[n];
  const int col = t * 128 + lane * 2;   // global col in 3072
  const int cc = col - h * 512;         // col within head
  const char* base = (const char*)Whb + (size_t)col * 2;
  float a0 = 0.f, a1 = 0.f;
#pragma unroll 4
  for (int j = 0; j < c; j++) {
    int2 e = se[w][j];
    ushort2 v = *(const ushort2*)(base + e.x);
    float wv = __int_as_float(e.y);
    a0 += wv * h2f(v.x);
    a1 += wv * h2f(v.y);
  }
  ushort2 o;
  o.x = f2h(a0);
  o.y = f2h(a1);
  *(ushort2*)(aggb + ((size_t)h * N_NODES + n) * 512 + cc) = o;
}

// ---------------- layer 3 reduce: head-sum + elu + L2-normalize ----------------
__global__ __launch_bounds__(256) void reduce3(const unsigned short* __restrict__ aggb,
                                               float* __restrict__ out) {
  __shared__ float buf[4];
  const int n = blockIdx.x, tid = threadIdx.x;
  float v0 = 0.f, v1 = 0.f;
#pragma unroll
  for (int h = 0; h < 6; h++) {
    ushort2 u = *(const ushort2*)(aggb + ((size_t)h * N_NODES + n) * 512 + tid * 2);
    v0 += h2f(u.x);
    v1 += h2f(u.y);
  }
  v0 = v0 > 0.f ? v0 : __expf(v0) - 1.f;
  v1 = v1 > 0.f ? v1 : __expf(v1) - 1.f;
  float ss = block_sum(v0 * v0 + v1 * v1, buf);
  float inv = 1.f / fmaxf(sqrtf(ss), 1e-12f);
  out[(size_t)n * 512 + tid * 2] = v0 * inv;
  out[(size_t)n * 512 + tid * 2 + 1] = v1 * inv;
}

extern "C" void kernel_launch(void* const* d_in, const int* in_sizes, int n_in,
                              void* d_out, int out_size, void* d_ws, size_t ws_size,
                              hipStream_t stream) {
  (void)in_sizes; (void)n_in; (void)out_size; (void)ws_size;
  const float* x   = (const float*)d_in[0];  // [4096, 2048]
  const float* adj = (const float*)d_in[1];  // [4096, 4096]
  const float* W1  = (const float*)d_in[2];  // [4, 2048, 256]
  const float* a1  = (const float*)d_in[3];  // [4, 512]
  const float* W2  = (const float*)d_in[4];  // [4, 1024, 256]
  const float* a2  = (const float*)d_in[5];  // [4, 512]
  const float* W3  = (const float*)d_in[6];  // [6, 1024, 512]
  const float* a3  = (const float*)d_in[7];  // [6, 1024]
  float* out = (float*)d_out;                // [4096, 512]

  // workspace layout (~76 MB peak)
  char* ws = (char*)d_ws;
  size_t off = 0;
  auto alloc = [&](size_t bytes) {
    void* p = ws + off;
    off += (bytes + 255) & ~(size_t)255;
    return p;
  };
  int* nbr_cnt = (int*)alloc((size_t)N_NODES * 4);
  int* nbr_idx = (int*)alloc((size_t)N_NODES * MAXNB * 4);
  float* fbuf = (float*)alloc((size_t)28 * N_NODES * 4);
  unsigned short* Wt = (unsigned short*)alloc((size_t)6 * 1024 * 512 * 2);  // 6.3 MB
  unsigned short* Areg = (unsigned short*)alloc((size_t)N_NODES * 2048 * 2);  // 16.8 MB
  unsigned short* Whb = (unsigned short*)alloc((size_t)N_NODES * 3072 * 2);   // 25.2 MB
  unsigned short* aggb = (unsigned short*)alloc((size_t)6 * N_NODES * 512 * 2);  // 25.2 MB

  // Areg timeline: xh (dead after gemm1) -> [wgt12 8.4 MB | hh 8.4 MB] ->
  // after gemm3: wgt3 (12.6 MB, overlaps dead region)
  unsigned short* xh = Areg;
  float* wgt12 = (float*)Areg;
  unsigned short* hh = Areg + (size_t)N_NODES * 1024;
  float* wgt3 = (float*)Areg;

  float* f1_1 = fbuf;
  float* f2_1 = fbuf + 4 * N_NODES;
  float* f1_2 = fbuf + 8 * N_NODES;
  float* f2_2 = fbuf + 12 * N_NODES;
  float* f1_3 = fbuf + 16 * N_NODES;
  float* f2_3 = fbuf + 22 * N_NODES;

  zero_f<<<(28 * N_NODES + 255) / 256, 256, 0, stream>>>(fbuf, 28 * N_NODES);
  build_csr<<<N_NODES, 256, 0, stream>>>(adj, nbr_cnt, nbr_idx);

  // ---- layer 1: A = x (K=2048), Ntot = 1024, D = 256 ----
  convert_h<<<(N_NODES * 2048 / 4 + 255) / 256, 256, 0, stream>>>(
      x, xh, N_NODES * 2048 / 4);
  convert_w<<<dim3(2048 / 32, 256 / 32, 4), 256, 0, stream>>>(W1, Wt, 2048, 256);
  gemm_mfma<<<dim3(N_NODES / BM, 1024 / BN), 256, 0, stream>>>(
      xh, Wt, Whb, f1_1, f2_1, a1, 2048, 1024, 256);
  attw<<<N_NODES, 256, 0, stream>>>(f1_1, f2_1, nbr_cnt, nbr_idx, wgt12, 4, 1.f);
  gather12<<<8 * (N_NODES / 4), 256, 0, stream>>>(Whb, wgt12, nbr_cnt, nbr_idx, hh);

  // ---- layer 2: A = h (K=1024), Ntot = 1024, D = 256 ----
  convert_w<<<dim3(1024 / 32, 256 / 32, 4), 256, 0, stream>>>(W2, Wt, 1024, 256);
  gemm_mfma<<<dim3(N_NODES / BM, 1024 / BN), 256, 0, stream>>>(
      hh, Wt, Whb, f1_2, f2_2, a2, 1024, 1024, 256);
  attw<<<N_NODES, 256, 0, stream>>>(f1_2, f2_2, nbr_cnt, nbr_idx, wgt12, 4, 1.f);
  gather12<<<8 * (N_NODES / 4), 256, 0, stream>>>(Whb, wgt12, nbr_cnt, nbr_idx, hh);

  // ---- layer 3: A = h (K=1024), Ntot = 3072, D = 512 ----
  convert_w<<<dim3(1024 / 32, 512 / 32, 6), 256, 0, stream>>>(W3, Wt, 1024, 512);
  gemm_mfma<<<dim3(N_NODES / BM, 3072 / BN), 256, 0, stream>>>(
      hh, Wt, Whb, f1_3, f2_3, a3, 1024, 3072, 512);
  attw<<<N_NODES, 256, 0, stream>>>(f1_3, f2_3, nbr_cnt, nbr_idx, wgt3, 6, 1.f / 6.f);
  gather3<<<24 * (N_NODES / 4), 256, 0, stream>>>(Whb, wgt3, nbr_cnt, nbr_idx, aggb);
  reduce3<<<N_NODES, 256, 0, stream>>>(aggb, out);
}